// Round 11
// baseline (24.020 us; speedup 1.0000x reference)
//
#include <hip/hip_runtime.h>

#define NN 1000000
#define NG 20000
#define C_ 10
#define M_ 50
#define G_ 8
#define CHUNK 512

typedef float f32x4 __attribute__((ext_vector_type(4)));

// ---------------------------------------------------------------------------
// Single fused kernel, single-writer (no atomics, no memset), ~4.5 KB LDS,
// 512-node chunks (1954 blocks ~ 7.6/CU). Per block:
//  A: per-wave int-width detect (ballot of 128 odd words; P_false = 50^-128)
//     | stage batch -> sb (LDS) | sZB/sZP log-sum-exp from global B/Pi
//     (no max-sub: |B|,|Pi| <= ~10 -> exp <= e^10, f32-safe)
//  B: lik table (stride 9) + hst argmax NIBBLE-PACKED (hpack[m], 4b/gen)
//  C (D1): h_states stream: x read DIRECT FROM GLOBAL inside the store loop
//     (read burst overlaps the 32 MB nontemporal write stream), nibble
//     unpack + cvt, coalesced f32x4 stores.
//  D (D2): per-wave segment sums: head iff batch changes (ballot over sb);
//     segment end via ballot scan (sb locally, global batch past the edge);
//     gather lik[x[n]] with x from L2 (hot from D1), 3-shuffle reduce, PLAIN
//     store. Empty graphs zeroed by the uniquely-owning adjacent head.
//     Every out element written exactly once -> bit-deterministic.
// ---------------------------------------------------------------------------
__global__ __launch_bounds__(256) void k_fused(const float* __restrict__ B,
                                               const float* __restrict__ Pi,
                                               const int* __restrict__ x,
                                               const int* __restrict__ batch,
                                               float* __restrict__ out,
                                               float* __restrict__ outh) {
    __shared__ float sZB[C_ * G_];       // log sum exp over M per (c,g)
    __shared__ float sZP[G_];            // log sum exp over C per g
    __shared__ float lik[M_ * 9];        // stride 9: gcd(9,32)=1, ~2-way conflicts
    __shared__ unsigned int hpack[M_];   // 8 argmax nibbles per label
    __shared__ int sb[CHUNK + 1];        // sb[0] = batch[base-1] or -1

    const int t = threadIdx.x;
    const int lane = t & 63;
    const int w = t >> 6;
    const int base = blockIdx.x * CHUNK;
    const int limit = (NN - base < CHUNK) ? (NN - base) : CHUNK;  // multiple of 4

    // ---- per-wave detect: x in [0,50) -> if int64, all odd words zero
    const int vdet = x[2 * lane + 1] | x[128 + 2 * lane + 1];
    const int is64 = (__ballot(vdet != 0) == 0ULL) ? 1 : 0;

    // ---- stage batch -> sb (coalesced int4) | log-sum-exps (overlapped)
    if (is64) {
        const int4* bq = (const int4*)batch + (base >> 1);   // 2 int64 per int4
        for (int i = t; i < (limit >> 1); i += 256) {
            const int4 b2 = bq[i];
            sb[1 + 2 * i] = b2.x; sb[2 + 2 * i] = b2.z;
        }
    } else {
        const int4* bq = (const int4*)batch + (base >> 2);
        for (int i = t; i < (limit >> 2); i += 256) {
            const int4 b2 = bq[i];
            sb[1 + 4 * i] = b2.x; sb[2 + 4 * i] = b2.y;
            sb[3 + 4 * i] = b2.z; sb[4 + 4 * i] = b2.w;
        }
    }
    if (t == 0)
        sb[0] = (base == 0) ? -1 : (is64 ? batch[2 * (base - 1)] : batch[base - 1]);

    if (t < 80) {
        const int c = t >> 3, g = t & 7;
        float Z = 0.f;
        for (int m = 0; m < M_; ++m) Z += __expf(B[(c * M_ + m) * G_ + g]);
        sZB[t] = __logf(Z);
    } else if (t < 88) {
        const int g = t - 80;
        float Z = 0.f;
        for (int c = 0; c < C_; ++c) Z += __expf(Pi[c * G_ + g]);
        sZP[g] = __logf(Z);
    }
    __syncthreads();

    // ---- tables: lik + nibble-packed argmax (B/Pi re-read, L1/L2-hot)
    for (int e = t; e < M_ * G_; e += 256) {
        const int m = e >> 3, g = e & 7;
        float s[C_];
        float bv = -1e30f;
        int bi = 0;
        for (int c = 0; c < C_; ++c) {
            const float v = (B[(c * M_ + m) * G_ + g] - sZB[c * G_ + g]) +
                            (Pi[c * G_ + g] - sZP[g]);
            s[c] = v;
            if (v > bv) { bv = v; bi = c; }  // strict > keeps FIRST max (jnp.argmax)
        }
        float Z = 0.f, W = 0.f;
        for (int c = 0; c < C_; ++c) {
            const float ee = __expf(s[c]);   // s in [-32,0]: no under/overflow
            Z += ee;
            W += ee * s[c];
        }
        lik[m * 9 + g] = W / Z;
        // pack 8 gens' argmax into one dword via aligned-8-lane-group shuffles
        unsigned int pk = 0;
#pragma unroll
        for (int g2 = 0; g2 < 8; ++g2)
            pk |= ((unsigned)__shfl(bi, (lane & ~7) + g2, 64) & 15u) << (4 * g2);
        if ((t & 7) == 0) hpack[m] = pk;
    }
    __syncthreads();

    // ---- D1: h_states stream — x direct from global (read || write overlap)
    f32x4* op = (f32x4*)outh + (size_t)base * 2;
    const int nf4 = limit * 2;
#pragma unroll 4
    for (int idx = t; idx < nf4; idx += 256) {
        const int n = base + (idx >> 1);
        const int xi = is64 ? x[2 * (size_t)n] : x[n];   // lane pairs share dword
        const unsigned int pk = hpack[xi];
        const int sh = (idx & 1) * 16;
        f32x4 v;
        v.x = (float)((pk >> (sh + 0)) & 15u);
        v.y = (float)((pk >> (sh + 4)) & 15u);
        v.z = (float)((pk >> (sh + 8)) & 15u);
        v.w = (float)((pk >> (sh + 12)) & 15u);
        __builtin_nontemporal_store(v, &op[idx]);
    }

    // ---- D2: per-wave segment sums (x via L2, hot from D1)
    for (int rr = 0; rr < CHUNK / 4 / 64; ++rr) {
        const int ib = (CHUNK / 4) * w + 64 * rr;
        const int i = ib + lane;
        const bool head = (i < limit) && (sb[1 + i] != sb[i]);
        unsigned long long hm = __ballot(head);
        while (hm) {
            const int i0 = ib + (int)__builtin_ctzll(hm);
            hm &= hm - 1;
            const int g  = sb[1 + i0];
            const int gp = sb[i0];
            if (lane < 8)                    // empty graphs in (gp, g): zero once
                for (int gg = gp + 1; gg < g; ++gg)
                    out[(size_t)gg * 8 + lane] = 0.f;

            const int n0 = base + i0;
            // find segment end: sb locally, global batch past the block edge
            int n_end = NN;
            for (int bse = n0; ; bse += 64) {
                const int ii = bse + lane;
                int val = g + 1;             // differs (also covers ii >= NN)
                if (ii < NN)
                    val = (ii < base + limit) ? sb[1 + ii - base]
                                              : (is64 ? batch[2 * (size_t)ii] : batch[ii]);
                const unsigned long long diff = __ballot(val != g);
                if (diff) { n_end = bse + (int)__builtin_ctzll(diff); break; }
            }

            const int ns = lane >> 3, r = lane & 7;
            float acc = 0.f;
            for (int n = n0 + ns; n < n_end; n += 8) {
                const int xi = is64 ? x[2 * (size_t)n] : x[n];
                acc += lik[xi * 9 + r];
            }
            acc += __shfl_xor(acc, 8, 64);
            acc += __shfl_xor(acc, 16, 64);
            acc += __shfl_xor(acc, 32, 64);
            if (lane < 8) out[(size_t)g * 8 + lane] = acc;

            if (n_end == NN && lane < 8)     // trailing empty graphs: zero once
                for (int gg = g + 1; gg < NG; ++gg)
                    out[(size_t)gg * 8 + lane] = 0.f;
        }
    }
}

// ---------------------------------------------------------------------------
extern "C" void kernel_launch(void* const* d_in, const int* in_sizes, int n_in,
                              void* d_out, int out_size, void* d_ws, size_t ws_size,
                              hipStream_t stream) {
    const int*   x     = (const int*)d_in[0];
    const int*   batch = (const int*)d_in[1];
    const float* B     = (const float*)d_in[2];
    const float* Pi    = (const float*)d_in[3];
    float* out  = (float*)d_out;             // likelihood [NG, G_] first
    float* outh = (float*)d_out + NG * G_;   // then h_states [NN, G_]

    k_fused<<<(NN + CHUNK - 1) / CHUNK, 256, 0, stream>>>(B, Pi, x, batch, out, outh);
}